// Round 8
// baseline (321.924 us; speedup 1.0000x reference)
//
#include <hip/hip_runtime.h>
#include <hip/hip_bf16.h>

using bf16 = __hip_bfloat16;
typedef __attribute__((ext_vector_type(8))) __bf16 bf16x8;
typedef __attribute__((ext_vector_type(4))) float f32x4;
typedef __attribute__((ext_vector_type(4))) short short4v;

#define GLB_AS(p) ((const __attribute__((address_space(1))) unsigned int*)(p))
#define LDS_AS(p) ((__attribute__((address_space(3))) unsigned int*)(p))

__device__ __forceinline__ void async_copy16(const void* g, void* l) {
  __builtin_amdgcn_global_load_lds(GLB_AS(g), LDS_AS(l), 16, 0, 0);
}

__device__ __forceinline__ f32x4 mfma16x16x32(bf16x8 a, bf16x8 b, f32x4 c) {
  return __builtin_amdgcn_mfma_f32_16x16x32_bf16(a, b, c, 0, 0, 0);
}

// k=16 MFMA: B-operand layout B[k=quad*4+i][n=lane&15] matches the S^T
// C-layout exactly -> P feeds PV straight from registers (no LDS round-trip).
__device__ __forceinline__ f32x4 mfma16x16x16(short4v a, short4v b, f32x4 c) {
  return __builtin_amdgcn_mfma_f32_16x16x16bf16_1k(a, b, c, 0, 0, 0);
}

__device__ __forceinline__ float bfu2f(unsigned short u) {
  union { unsigned int i; float f; } x;
  x.i = (unsigned int)u << 16;
  return x.f;
}

#define LOG2E 1.44269504f

// ---------------------------------------------------------------------------
// Hx (B,D,T) f32 -> hcat[b][t][0..1023] bf16 (row stride 2048). LDS transpose.
__global__ __launch_bounds__(256) void pack_hx(const float* __restrict__ Hx,
                                               bf16* __restrict__ hcat) {
  __shared__ float tile[64][65];
  const int t0 = blockIdx.x * 64, d0 = blockIdx.y * 64, b = blockIdx.z;
  const int c = threadIdx.x & 63, r0 = threadIdx.x >> 6;
#pragma unroll
  for (int i = 0; i < 16; ++i) {
    const int rd = r0 + i * 4;
    tile[rd][c] = Hx[((size_t)(b * 1024 + d0 + rd)) * 2048 + t0 + c];
  }
  __syncthreads();
#pragma unroll
  for (int i = 0; i < 16; ++i) {
    const int ct = r0 + i * 4;
    hcat[((size_t)(b * 2048 + t0 + ct)) * 2048 + d0 + c] =
        __float2bfloat16(tile[c][ct]);
  }
}

// ---------------------------------------------------------------------------
// One kernel for all f32->bf16 packs + the QKV bias concat (f32 copy).
__global__ __launch_bounds__(256) void pack_all(
    const float* __restrict__ Hf, const float* __restrict__ Wq,
    const float* __restrict__ Wk, const float* __restrict__ Wv,
    const float* __restrict__ Wo, const float* __restrict__ Wg,
    const float* __restrict__ Gm, const float* __restrict__ bq,
    const float* __restrict__ bk, const float* __restrict__ bv,
    bf16* __restrict__ hcat, bf16* __restrict__ Wqkvb, bf16* __restrict__ Wob,
    bf16* __restrict__ Wgb, bf16* __restrict__ Gmb,
    float* __restrict__ qkvbias) {
  const int gid = blockIdx.x * 256 + threadIdx.x;
  const float* src = nullptr;
  bf16* dst = nullptr;
  int lg = 0, ldo = 0, off = 0, idx = 0;
  bool zero = false;
  if (gid < 1048576) { idx = gid; src = Hf; dst = hcat; lg = 8; ldo = 2048; off = 1024; }
  else if (gid < 1572864) { idx = gid - 1048576; src = Wq; dst = Wqkvb; lg = 9; ldo = 2048; }
  else if (gid < 2097152) { idx = gid - 1572864; src = Wk; dst = Wqkvb + (size_t)1024 * 2048; lg = 9; ldo = 2048; }
  else if (gid < 2359296) { idx = gid - 2097152; src = Wv; dst = Wqkvb + (size_t)2048 * 2048; lg = 8; ldo = 2048; }
  else if (gid < 2621440) { idx = gid - 2359296; zero = true; dst = Wqkvb + (size_t)2048 * 2048 + 1024; lg = 8; ldo = 2048; }
  else if (gid < 2883584) { idx = gid - 2621440; src = Wo; dst = Wob; lg = 8; ldo = 1024; }
  else if (gid < 3014656) { idx = gid - 2883584; src = Wg; dst = Wgb; lg = 6; ldo = 256; }
  else if (gid < 3276800) { idx = gid - 3014656; src = Gm; dst = Gmb; lg = 6; ldo = 256; }
  else if (gid < 3277056) { const int i = gid - 3276800; ((float4*)qkvbias)[i] = ((const float4*)bq)[i]; return; }
  else if (gid < 3277312) { const int i = gid - 3277056; ((float4*)(qkvbias + 1024))[i] = ((const float4*)bk)[i]; return; }
  else { const int i = gid - 3277312; ((float4*)(qkvbias + 2048))[i] = ((const float4*)bv)[i]; return; }
  const int row = idx >> lg, c = idx & ((1 << lg) - 1);
  bf16* o = dst + (size_t)row * ldo + off + c * 4;
  __align__(8) bf16 tmp[4];
  if (zero) {
    tmp[0] = tmp[1] = tmp[2] = tmp[3] = __float2bfloat16(0.f);
  } else {
    const float4 v = ((const float4*)src)[(size_t)idx];
    tmp[0] = __float2bfloat16(v.x); tmp[1] = __float2bfloat16(v.y);
    tmp[2] = __float2bfloat16(v.z); tmp[3] = __float2bfloat16(v.w);
  }
  *(ushort4*)o = *(const ushort4*)tmp;
}

// ---------------------------------------------------------------------------
// Combined QKV + bias GEMM, BK=64, single-barrier dbuf K-loop, XCD-swizzled.
// 1D grid 1280. 128B LDS rows: swizzle slot = chunk ^ (row&7).
__global__ __launch_bounds__(256) void gemm_qkv_bias(
    const bf16* __restrict__ hcat, const bf16* __restrict__ Wqkv,
    const float* __restrict__ qkvbias, const bf16* __restrict__ Gmb,
    const bf16* __restrict__ Wgb, const float* __restrict__ bg,
    bf16* __restrict__ QKb, bf16* __restrict__ Vt, bf16* __restrict__ biasS) {
  __shared__ __align__(16) bf16 As[2][128 * 64];  // 2 x 16 KB
  __shared__ __align__(16) bf16 Bs[2][128 * 64];  // 2 x 16 KB
  const int lin = blockIdx.x;
  const int xcd = lin & 7;
  const int kk = lin >> 3;  // 0..159 per xcd
  const bool isqkv = kk < 96;
  int m_idx, n0;
  if (isqkv) {
    m_idx = kk / 3;
    n0 = (xcd * 3 + (kk - m_idx * 3)) * 128;
  } else {
    const int k2 = kk - 96;
    m_idx = k2 >> 1;
    n0 = (xcd * 2 + (k2 & 1)) * 128;
  }
  const int m0 = m_idx * 128;
  const bf16* A = isqkv ? hcat : Gmb;
  const bf16* W = isqkv ? Wqkv : Wgb;
  const float* biasv = isqkv ? qkvbias : bg;
  const int Kd = isqkv ? 2048 : 256;
  const int tid = threadIdx.x, lane = tid & 63, w = tid >> 6;
  const int wm = (w >> 1) * 64, wn = (w & 1) * 64;
  const int fr = lane & 15;
  const int ck = lane >> 4;

  f32x4 acc[4][4];
  const f32x4 fzero = {0.f, 0.f, 0.f, 0.f};
#pragma unroll
  for (int i = 0; i < 4; ++i)
#pragma unroll
    for (int j = 0; j < 4; ++j) acc[i][j] = fzero;

  auto stage = [&](int it, int buf) {
    const int k0 = it * 64;
#pragma unroll
    for (int is = 0; is < 4; ++is) {
      const int off = is * 4096 + w * 1024;      // byte offset in 16 KB buffer
      const int row = (off >> 7) + (lane >> 3);  // 128B rows
      const int sch = ((lane & 7) ^ (row & 7)) * 8;
      async_copy16(A + (size_t)(m0 + row) * Kd + k0 + sch,
                   (char*)As[buf] + off);
      async_copy16(W + (size_t)(n0 + row) * Kd + k0 + sch,
                   (char*)Bs[buf] + off);
    }
  };

  const int nit = Kd >> 6;
  stage(0, 0);
  __syncthreads();
  for (int it = 0; it < nit; ++it) {
    const int cur = it & 1;
    if (it + 1 < nit) stage(it + 1, cur ^ 1);
#pragma unroll
    for (int ks = 0; ks < 2; ++ks) {
      bf16x8 af[4], bfr[4];
#pragma unroll
      for (int i = 0; i < 4; ++i) {
        const int swk = (((ks * 4 + ck) ^ (fr & 7))) * 8;
        af[i] = *(const bf16x8*)(As[cur] + (wm + i * 16 + fr) * 64 + swk);
        bfr[i] = *(const bf16x8*)(Bs[cur] + (wn + i * 16 + fr) * 64 + swk);
      }
#pragma unroll
      for (int i = 0; i < 4; ++i)
#pragma unroll
        for (int j = 0; j < 4; ++j)
          acc[i][j] = mfma16x16x32(af[i], bfr[j], acc[i][j]);
    }
    __syncthreads();
  }
  const int erow = (lane >> 4) * 4;
  const int ecol = lane & 15;

  if (!isqkv) {
#pragma unroll
    for (int i = 0; i < 4; ++i) {
      const int gm0 = m0 + wm + i * 16 + erow;
#pragma unroll
      for (int j = 0; j < 4; ++j) {
        const int gn = n0 + wn + j * 16 + ecol;
        const float bv = biasv[gn];
#pragma unroll
        for (int r = 0; r < 4; ++r)
          biasS[(size_t)(gm0 + r) * 2048 + gn] =
              __float2bfloat16((acc[i][j][r] + bv) * LOG2E);
      }
    }
  } else if (n0 < 2048) {
    const float sc = (n0 < 1024) ? 0.125f * LOG2E : 1.0f;
#pragma unroll
    for (int i = 0; i < 4; ++i) {
      const int gm0 = m0 + wm + i * 16 + erow;
#pragma unroll
      for (int j = 0; j < 4; ++j) {
        const int gn = n0 + wn + j * 16 + ecol;
        const float bv = biasv[gn];
#pragma unroll
        for (int r = 0; r < 4; ++r)
          QKb[(size_t)(gm0 + r) * 2048 + gn] =
              __float2bfloat16((acc[i][j][r] + bv) * sc);
      }
    }
  } else {
#pragma unroll
    for (int i = 0; i < 4; ++i) {
      const int gm0 = m0 + wm + i * 16 + erow;
      const int bb = gm0 >> 11;
      const int t = gm0 & 2047;
#pragma unroll
      for (int j = 0; j < 4; ++j) {
        const int gn = n0 + wn + j * 16 + ecol;
        const float bv = biasv[gn];
        const int d = gn - 2048;
        __align__(8) bf16 tmp[4];
#pragma unroll
        for (int r = 0; r < 4; ++r)
          tmp[r] = __float2bfloat16(acc[i][j][r] + bv);
        *(ushort4*)(Vt + ((size_t)(bb * 1024 + d)) * 2048 + t) =
            *(const ushort4*)tmp;
      }
    }
  }
}

// ---------------------------------------------------------------------------
// Out projection: C(4096x1024) f32 = A(4096x1024)@(1024x1024)^T + bo.
// 128x64 tile, BK=64, dbuf, XCD-swizzled (2 n-blocks per XCD). 1D grid 512.
__global__ __launch_bounds__(256) void gemm_out(const bf16* __restrict__ A,
                                                const bf16* __restrict__ W,
                                                const float* __restrict__ biasv,
                                                float* __restrict__ C) {
  __shared__ __align__(16) bf16 As[2][128 * 64];  // 2 x 16 KB
  __shared__ __align__(16) bf16 Bs[2][64 * 64];   // 2 x 8 KB
  const int lin = blockIdx.x;
  const int xcd = lin & 7;
  const int kk = lin >> 3;  // 0..63
  const int m0 = (kk >> 1) * 128;
  const int n0 = (xcd * 2 + (kk & 1)) * 64;
  const int tid = threadIdx.x, lane = tid & 63, w = tid >> 6;
  const int wm = (w >> 1) * 64, wn = (w & 1) * 32;
  const int fr = lane & 15;
  const int ck = lane >> 4;

  f32x4 acc[4][2];
  const f32x4 fzero = {0.f, 0.f, 0.f, 0.f};
#pragma unroll
  for (int i = 0; i < 4; ++i)
#pragma unroll
    for (int j = 0; j < 2; ++j) acc[i][j] = fzero;

  auto stage = [&](int it, int buf) {
    const int k0 = it * 64;
#pragma unroll
    for (int is = 0; is < 4; ++is) {
      const int off = is * 4096 + w * 1024;
      const int row = (off >> 7) + (lane >> 3);
      const int sch = ((lane & 7) ^ (row & 7)) * 8;
      async_copy16(A + (size_t)(m0 + row) * 1024 + k0 + sch,
                   (char*)As[buf] + off);
      if (is < 2)
        async_copy16(W + (size_t)(n0 + row) * 1024 + k0 + sch,
                     (char*)Bs[buf] + off);
    }
  };

  stage(0, 0);
  __syncthreads();
  for (int it = 0; it < 16; ++it) {
    const int cur = it & 1;
    if (it + 1 < 16) stage(it + 1, cur ^ 1);
#pragma unroll
    for (int ks = 0; ks < 2; ++ks) {
      bf16x8 af[4], bfr[2];
      const int swk0 = (((ks * 4 + ck) ^ (fr & 7))) * 8;
#pragma unroll
      for (int i = 0; i < 4; ++i)
        af[i] = *(const bf16x8*)(As[cur] + (wm + i * 16 + fr) * 64 + swk0);
#pragma unroll
      for (int j = 0; j < 2; ++j)
        bfr[j] = *(const bf16x8*)(Bs[cur] + (wn + j * 16 + fr) * 64 + swk0);
#pragma unroll
      for (int i = 0; i < 4; ++i)
#pragma unroll
        for (int j = 0; j < 2; ++j)
          acc[i][j] = mfma16x16x32(af[i], bfr[j], acc[i][j]);
    }
    __syncthreads();
  }
  const int erow = (lane >> 4) * 4;
  const int ecol = lane & 15;
#pragma unroll
  for (int i = 0; i < 4; ++i) {
    const int gm0 = m0 + wm + i * 16 + erow;
#pragma unroll
    for (int j = 0; j < 2; ++j) {
      const int gn = n0 + wn + j * 16 + ecol;
      const float bv = biasv[gn];
#pragma unroll
      for (int r = 0; r < 4; ++r)
        C[(size_t)(gm0 + r) * 1024 + gn] = acc[i][j][r] + bv;
    }
  }
}

// ---------------------------------------------------------------------------
// Flash attention, S^T formulation, no-max softmax, key-split, REGISTER P:
// S^T = K.Q^T via 16x16x32 (C-init = bias); its C-layout (lane: q=lane&15,
// keys=quad*4+r) IS the B-operand layout of 16x16x16 -> PV computes
// O^T[d][q] = V^T . P^T with A = V^T-frags from Vs (b64) and B = exp'd P
// packed in regs. No P LDS buffer at all. 2-barrier staging loop.
// XCD-swizzled combos. 1D grid 1024 (16 q-blk x 2 halves x 32 (h,b)).
// LDS 16.4 KB.
__global__ __launch_bounds__(256) void flash_attn(
    const bf16* __restrict__ Qm, const bf16* __restrict__ Km,
    const bf16* __restrict__ Vtm, const bf16* __restrict__ biasS,
    float* __restrict__ Op0, float* __restrict__ Op1,
    float* __restrict__ lpart) {
  __shared__ __align__(16) bf16 Ks[64 * 64];  // 8 KB [key][d] swizzled
  __shared__ __align__(16) bf16 Vs[64 * 64];  // 8 KB [d][key] swizzled
  const int lin = blockIdx.x;
  const int xcd = lin & 7;
  const int kk = lin >> 3;        // 0..127
  const int cl = kk & 3;          // combo local
  const int r2 = kk >> 2;         // 0..31
  const int half = r2 & 1;
  const int q0 = (r2 >> 1) * 128;
  const int combo = xcd * 4 + cl; // 0..31
  const int h = combo & 15;
  const int b = combo >> 4;
  const int tid = threadIdx.x, lane = tid & 63, w = tid >> 6;
  const int ql = lane & 15, qk = lane >> 4;
  const int T = 2048, D = 1024;
  const int sw0 = (qk ^ (ql & 7)) * 8;
  const int sw1 = ((qk + 4) ^ (ql & 7)) * 8;

  // Q B-frags for QK^T: B[n=q][k=d], two q-subtiles x two 32-d k-steps
  bf16x8 qf[2][2];
#pragma unroll
  for (int qt = 0; qt < 2; ++qt)
#pragma unroll
    for (int ks = 0; ks < 2; ++ks)
      qf[qt][ks] = *(const bf16x8*)(
          Qm + (size_t)(b * T + q0 + w * 32 + qt * 16 + ql) * 2048 + h * 64 +
          ks * 32 + qk * 8);

  // O^T accumulators: acc[dt][qt], D rows = d (quad*4+r), cols = q
  f32x4 acc[4][2];
  const f32x4 fzero = {0.f, 0.f, 0.f, 0.f};
#pragma unroll
  for (int dt = 0; dt < 4; ++dt)
#pragma unroll
    for (int qt = 0; qt < 2; ++qt) acc[dt][qt] = fzero;
  float lp[2] = {0.f, 0.f};

  const bf16* kbase = Km + (size_t)(b * T) * 2048 + h * 64;
  const bf16* vbase = Vtm + (size_t)(b * D + h * 64) * 2048;
  const bf16* bb0 = biasS + (size_t)(b * T + q0 + w * 32 + ql) * 2048 + qk * 4;

  for (int j = 0; j < 16; ++j) {
    const int jj = half * 16 + j;  // global key-block
    __syncthreads();
#pragma unroll
    for (int is = 0; is < 2; ++is) {
      const int off = is * 4096 + w * 1024;
      const int row = (off >> 7) + (lane >> 3);
      const int sch = ((lane & 7) ^ (row & 7)) * 8;
      async_copy16(kbase + (size_t)(jj * 64 + row) * 2048 + sch,
                   (char*)Ks + off);
      async_copy16(vbase + (size_t)row * 2048 + jj * 64 + sch, (char*)Vs + off);
    }
    // bias prefetch (overlaps staging drain)
    ushort4 bq[2][4];
#pragma unroll
    for (int qt = 0; qt < 2; ++qt)
#pragma unroll
      for (int jt = 0; jt < 4; ++jt)
        bq[qt][jt] = *(const ushort4*)(bb0 + (size_t)qt * 16 * 2048 + jj * 64 +
                                       jt * 16);
    __syncthreads();
    // per 16-key tile jt: S^T -> exp -> packed B-frag -> PV (k=16)
#pragma unroll
    for (int jt = 0; jt < 4; ++jt) {
      const bf16x8 kf0 = *(const bf16x8*)(Ks + (jt * 16 + ql) * 64 + sw0);
      const bf16x8 kf1 = *(const bf16x8*)(Ks + (jt * 16 + ql) * 64 + sw1);
      short4v pfr[2];
#pragma unroll
      for (int qt = 0; qt < 2; ++qt) {
        f32x4 c;
        c[0] = bfu2f(bq[qt][jt].x); c[1] = bfu2f(bq[qt][jt].y);
        c[2] = bfu2f(bq[qt][jt].z); c[3] = bfu2f(bq[qt][jt].w);
        c = mfma16x16x32(kf0, qf[qt][0], c);
        c = mfma16x16x32(kf1, qf[qt][1], c);
        __align__(8) bf16 t4[4];
#pragma unroll
        for (int r = 0; r < 4; ++r) {
          const float pv = __builtin_amdgcn_exp2f(c[r]);
          lp[qt] += pv;
          t4[r] = __float2bfloat16(pv);
        }
        pfr[qt] = *(const short4v*)t4;
      }
      // O^T += V^T-frag x P^T-frag ; A-frag shared across qt
#pragma unroll
      for (int dt = 0; dt < 4; ++dt) {
        const int slot = ((jt * 2 + (qk >> 1)) ^ (ql & 7)) * 8 + (qk & 1) * 4;
        const short4v vf = *(const short4v*)(Vs + (dt * 16 + ql) * 64 + slot);
        acc[dt][0] = mfma16x16x16(vf, pfr[0], acc[dt][0]);
        acc[dt][1] = mfma16x16x16(vf, pfr[1], acc[dt][1]);
      }
    }
  }
  // l partial: reduce across quads (lane's p-values all share q = ...+ql)
#pragma unroll
  for (int qt = 0; qt < 2; ++qt) {
    lp[qt] += __shfl_xor(lp[qt], 16);
    lp[qt] += __shfl_xor(lp[qt], 32);
  }
  if (qk == 0) {
#pragma unroll
    for (int qt = 0; qt < 2; ++qt)
      lpart[half * 65536 + (b * 16 + h) * 2048 + q0 + w * 32 + qt * 16 + ql] =
          lp[qt];
  }
  // epilogue: O^T C-layout -> lane holds q=ql, d = dt*16 + qk*4 + r
  float* Op = half ? Op1 : Op0;
#pragma unroll
  for (int qt = 0; qt < 2; ++qt) {
    const size_t orow = (size_t)(b * T + q0 + w * 32 + qt * 16 + ql);
#pragma unroll
    for (int dt = 0; dt < 4; ++dt) {
      float4 v;
      v.x = acc[dt][qt][0]; v.y = acc[dt][qt][1];
      v.z = acc[dt][qt][2]; v.w = acc[dt][qt][3];
      *(float4*)(Op + orow * 1024 + h * 64 + dt * 16 + qk * 4) = v;
    }
  }
}

// ---------------------------------------------------------------------------
// Combine key-half partials: AOut = bf16((O0+O1) / (l0+l1)). grid 4096 x 256.
__global__ __launch_bounds__(256) void combine(const float* __restrict__ O0,
                                               const float* __restrict__ O1,
                                               const float* __restrict__ lpart,
                                               bf16* __restrict__ AOut) {
  const int idx = blockIdx.x * 256 + threadIdx.x;  // 0..1048575
  const int row = idx >> 8;
  const int col = (idx & 255) * 4;
  const int b = row >> 11, q = row & 2047, h = col >> 6;
  const int li = (b * 16 + h) * 2048 + q;
  const float inv = __builtin_amdgcn_rcpf(lpart[li] + lpart[65536 + li]);
  const float4 a = *(const float4*)(O0 + (size_t)row * 1024 + col);
  const float4 c = *(const float4*)(O1 + (size_t)row * 1024 + col);
  __align__(8) bf16 t[4] = {
      __float2bfloat16((a.x + c.x) * inv), __float2bfloat16((a.y + c.y) * inv),
      __float2bfloat16((a.z + c.z) * inv), __float2bfloat16((a.w + c.w) * inv)};
  *(ushort4*)(AOut + (size_t)row * 1024 + col) = *(const ushort4*)t;
}

// ---------------------------------------------------------------------------
extern "C" void kernel_launch(void* const* d_in, const int* in_sizes, int n_in,
                              void* d_out, int out_size, void* d_ws,
                              size_t ws_size, hipStream_t stream) {
  (void)in_sizes; (void)n_in; (void)out_size; (void)ws_size;
  const float* Hx = (const float*)d_in[0];
  const float* Hf = (const float*)d_in[1];
  const float* Gm = (const float*)d_in[2];
  const float* Wg = (const float*)d_in[3];
  const float* bg = (const float*)d_in[4];
  const float* Wq = (const float*)d_in[5];
  const float* bq = (const float*)d_in[6];
  const float* Wk = (const float*)d_in[7];
  const float* bk = (const float*)d_in[8];
  const float* Wv = (const float*)d_in[9];
  const float* bv = (const float*)d_in[10];
  const float* Wo = (const float*)d_in[11];
  const float* bo = (const float*)d_in[12];
  float* out = (float*)d_out;

  char* p = (char*)d_ws;
  bf16* hcat = (bf16*)p;   p += (size_t)4096 * 2048 * 2;  // (B*T, 2D)
  bf16* QKb = (bf16*)p;    p += (size_t)4096 * 2048 * 2;  // (B*T, Q|K)
  bf16* Vtb = (bf16*)p;    p += (size_t)4096 * 1024 * 2;  // (B, D, T)
  bf16* biasS = (bf16*)p;  p += (size_t)4096 * 2048 * 2;  // (B*T, T) * log2e
  bf16* AOut = (bf16*)p;   p += (size_t)4096 * 1024 * 2;
  bf16* Wqkvb = (bf16*)p;  p += (size_t)3072 * 2048 * 2;  // (3N, K) packed
  bf16* Wob = (bf16*)p;    p += (size_t)1024 * 1024 * 2;
  bf16* Wgb = (bf16*)p;    p += (size_t)2048 * 256 * 2;
  bf16* Gmb = (bf16*)p;    p += (size_t)4096 * 256 * 2;
  float* qkvbias = (float*)p; p += (size_t)3072 * 4;
  float* Op1 = (float*)p;  p += (size_t)4096 * 1024 * 4;  // key-half-1 partial
  float* lpart = (float*)p; p += (size_t)2 * 65536 * 4;   // l partials
  float* Op0 = (float*)hcat;  // hcat is dead after gemm_qkv_bias; 16.8 MB fits

  pack_hx<<<dim3(32, 16, 2), 256, 0, stream>>>(Hx, hcat);
  pack_all<<<dim3(12803), 256, 0, stream>>>(Hf, Wq, Wk, Wv, Wo, Wg, Gm, bq, bk,
                                            bv, hcat, Wqkvb, Wob, Wgb, Gmb,
                                            qkvbias);
  // QKV projection + attention-bias GEMM, one dispatch, XCD-swizzled
  gemm_qkv_bias<<<dim3(1280), 256, 0, stream>>>(hcat, Wqkvb, qkvbias, Gmb,
                                                Wgb, bg, QKb, Vtb, biasS);
  // fused attention, key-split halves, register-P
  flash_attn<<<dim3(1024), 256, 0, stream>>>(QKb, QKb + 1024, Vtb, biasS,
                                             Op0, Op1, lpart);
  // combine partials -> AOut bf16
  combine<<<dim3(4096), 256, 0, stream>>>(Op0, Op1, lpart, AOut);
  // output projection (fp32 out), XCD-swizzled
  gemm_out<<<dim3(512), 256, 0, stream>>>(AOut, Wob, bo, out);
}

// Round 9
// 292.465 us; speedup vs baseline: 1.1007x; 1.1007x over previous
//
#include <hip/hip_runtime.h>
#include <hip/hip_bf16.h>

using bf16 = __hip_bfloat16;
typedef __attribute__((ext_vector_type(8))) __bf16 bf16x8;
typedef __attribute__((ext_vector_type(4))) float f32x4;

#define GLB_AS(p) ((const __attribute__((address_space(1))) unsigned int*)(p))
#define LDS_AS(p) ((__attribute__((address_space(3))) unsigned int*)(p))

__device__ __forceinline__ void async_copy16(const void* g, void* l) {
  __builtin_amdgcn_global_load_lds(GLB_AS(g), LDS_AS(l), 16, 0, 0);
}

__device__ __forceinline__ f32x4 mfma16x16x32(bf16x8 a, bf16x8 b, f32x4 c) {
  return __builtin_amdgcn_mfma_f32_16x16x32_bf16(a, b, c, 0, 0, 0);
}

__device__ __forceinline__ float bfu2f(unsigned short u) {
  union { unsigned int i; float f; } x;
  x.i = (unsigned int)u << 16;
  return x.f;
}

#define LOG2E 1.44269504f

// ---------------------------------------------------------------------------
// Hx (B,D,T) f32 -> hcat[b][t][0..1023] bf16 (row stride 2048). LDS transpose.
__global__ __launch_bounds__(256) void pack_hx(const float* __restrict__ Hx,
                                               bf16* __restrict__ hcat) {
  __shared__ float tile[64][65];
  const int t0 = blockIdx.x * 64, d0 = blockIdx.y * 64, b = blockIdx.z;
  const int c = threadIdx.x & 63, r0 = threadIdx.x >> 6;
#pragma unroll
  for (int i = 0; i < 16; ++i) {
    const int rd = r0 + i * 4;
    tile[rd][c] = Hx[((size_t)(b * 1024 + d0 + rd)) * 2048 + t0 + c];
  }
  __syncthreads();
#pragma unroll
  for (int i = 0; i < 16; ++i) {
    const int ct = r0 + i * 4;
    hcat[((size_t)(b * 2048 + t0 + ct)) * 2048 + d0 + c] =
        __float2bfloat16(tile[c][ct]);
  }
}

// ---------------------------------------------------------------------------
// One kernel for all f32->bf16 packs + the QKV bias concat (f32 copy).
__global__ __launch_bounds__(256) void pack_all(
    const float* __restrict__ Hf, const float* __restrict__ Wq,
    const float* __restrict__ Wk, const float* __restrict__ Wv,
    const float* __restrict__ Wo, const float* __restrict__ Wg,
    const float* __restrict__ Gm, const float* __restrict__ bq,
    const float* __restrict__ bk, const float* __restrict__ bv,
    bf16* __restrict__ hcat, bf16* __restrict__ Wqkvb, bf16* __restrict__ Wob,
    bf16* __restrict__ Wgb, bf16* __restrict__ Gmb,
    float* __restrict__ qkvbias) {
  const int gid = blockIdx.x * 256 + threadIdx.x;
  const float* src = nullptr;
  bf16* dst = nullptr;
  int lg = 0, ldo = 0, off = 0, idx = 0;
  bool zero = false;
  if (gid < 1048576) { idx = gid; src = Hf; dst = hcat; lg = 8; ldo = 2048; off = 1024; }
  else if (gid < 1572864) { idx = gid - 1048576; src = Wq; dst = Wqkvb; lg = 9; ldo = 2048; }
  else if (gid < 2097152) { idx = gid - 1572864; src = Wk; dst = Wqkvb + (size_t)1024 * 2048; lg = 9; ldo = 2048; }
  else if (gid < 2359296) { idx = gid - 2097152; src = Wv; dst = Wqkvb + (size_t)2048 * 2048; lg = 8; ldo = 2048; }
  else if (gid < 2621440) { idx = gid - 2359296; zero = true; dst = Wqkvb + (size_t)2048 * 2048 + 1024; lg = 8; ldo = 2048; }
  else if (gid < 2883584) { idx = gid - 2621440; src = Wo; dst = Wob; lg = 8; ldo = 1024; }
  else if (gid < 3014656) { idx = gid - 2883584; src = Wg; dst = Wgb; lg = 6; ldo = 256; }
  else if (gid < 3276800) { idx = gid - 3014656; src = Gm; dst = Gmb; lg = 6; ldo = 256; }
  else if (gid < 3277056) { const int i = gid - 3276800; ((float4*)qkvbias)[i] = ((const float4*)bq)[i]; return; }
  else if (gid < 3277312) { const int i = gid - 3277056; ((float4*)(qkvbias + 1024))[i] = ((const float4*)bk)[i]; return; }
  else { const int i = gid - 3277312; ((float4*)(qkvbias + 2048))[i] = ((const float4*)bv)[i]; return; }
  const int row = idx >> lg, c = idx & ((1 << lg) - 1);
  bf16* o = dst + (size_t)row * ldo + off + c * 4;
  __align__(8) bf16 tmp[4];
  if (zero) {
    tmp[0] = tmp[1] = tmp[2] = tmp[3] = __float2bfloat16(0.f);
  } else {
    const float4 v = ((const float4*)src)[(size_t)idx];
    tmp[0] = __float2bfloat16(v.x); tmp[1] = __float2bfloat16(v.y);
    tmp[2] = __float2bfloat16(v.z); tmp[3] = __float2bfloat16(v.w);
  }
  *(ushort4*)o = *(const ushort4*)tmp;
}

// ---------------------------------------------------------------------------
// Combined QKV + bias GEMM, BK=64, single-barrier dbuf K-loop, XCD-swizzled.
// 1D grid 1280. 128B LDS rows: swizzle slot = chunk ^ (row&7).
__global__ __launch_bounds__(256) void gemm_qkv_bias(
    const bf16* __restrict__ hcat, const bf16* __restrict__ Wqkv,
    const float* __restrict__ qkvbias, const bf16* __restrict__ Gmb,
    const bf16* __restrict__ Wgb, const float* __restrict__ bg,
    bf16* __restrict__ QKb, bf16* __restrict__ Vt, bf16* __restrict__ biasS) {
  __shared__ __align__(16) bf16 As[2][128 * 64];  // 2 x 16 KB
  __shared__ __align__(16) bf16 Bs[2][128 * 64];  // 2 x 16 KB
  const int lin = blockIdx.x;
  const int xcd = lin & 7;
  const int kk = lin >> 3;  // 0..159 per xcd
  const bool isqkv = kk < 96;
  int m_idx, n0;
  if (isqkv) {
    m_idx = kk / 3;
    n0 = (xcd * 3 + (kk - m_idx * 3)) * 128;
  } else {
    const int k2 = kk - 96;
    m_idx = k2 >> 1;
    n0 = (xcd * 2 + (k2 & 1)) * 128;
  }
  const int m0 = m_idx * 128;
  const bf16* A = isqkv ? hcat : Gmb;
  const bf16* W = isqkv ? Wqkv : Wgb;
  const float* biasv = isqkv ? qkvbias : bg;
  const int Kd = isqkv ? 2048 : 256;
  const int tid = threadIdx.x, lane = tid & 63, w = tid >> 6;
  const int wm = (w >> 1) * 64, wn = (w & 1) * 64;
  const int fr = lane & 15;
  const int ck = lane >> 4;

  f32x4 acc[4][4];
  const f32x4 fzero = {0.f, 0.f, 0.f, 0.f};
#pragma unroll
  for (int i = 0; i < 4; ++i)
#pragma unroll
    for (int j = 0; j < 4; ++j) acc[i][j] = fzero;

  auto stage = [&](int it, int buf) {
    const int k0 = it * 64;
#pragma unroll
    for (int is = 0; is < 4; ++is) {
      const int off = is * 4096 + w * 1024;      // byte offset in 16 KB buffer
      const int row = (off >> 7) + (lane >> 3);  // 128B rows
      const int sch = ((lane & 7) ^ (row & 7)) * 8;
      async_copy16(A + (size_t)(m0 + row) * Kd + k0 + sch,
                   (char*)As[buf] + off);
      async_copy16(W + (size_t)(n0 + row) * Kd + k0 + sch,
                   (char*)Bs[buf] + off);
    }
  };

  const int nit = Kd >> 6;
  stage(0, 0);
  __syncthreads();
  for (int it = 0; it < nit; ++it) {
    const int cur = it & 1;
    if (it + 1 < nit) stage(it + 1, cur ^ 1);
#pragma unroll
    for (int ks = 0; ks < 2; ++ks) {
      bf16x8 af[4], bfr[4];
#pragma unroll
      for (int i = 0; i < 4; ++i) {
        const int swk = (((ks * 4 + ck) ^ (fr & 7))) * 8;
        af[i] = *(const bf16x8*)(As[cur] + (wm + i * 16 + fr) * 64 + swk);
        bfr[i] = *(const bf16x8*)(Bs[cur] + (wn + i * 16 + fr) * 64 + swk);
      }
#pragma unroll
      for (int i = 0; i < 4; ++i)
#pragma unroll
        for (int j = 0; j < 4; ++j)
          acc[i][j] = mfma16x16x32(af[i], bfr[j], acc[i][j]);
    }
    __syncthreads();
  }
  const int erow = (lane >> 4) * 4;
  const int ecol = lane & 15;

  if (!isqkv) {
#pragma unroll
    for (int i = 0; i < 4; ++i) {
      const int gm0 = m0 + wm + i * 16 + erow;
#pragma unroll
      for (int j = 0; j < 4; ++j) {
        const int gn = n0 + wn + j * 16 + ecol;
        const float bv = biasv[gn];
#pragma unroll
        for (int r = 0; r < 4; ++r)
          biasS[(size_t)(gm0 + r) * 2048 + gn] =
              __float2bfloat16((acc[i][j][r] + bv) * LOG2E);
      }
    }
  } else if (n0 < 2048) {
    const float sc = (n0 < 1024) ? 0.125f * LOG2E : 1.0f;
#pragma unroll
    for (int i = 0; i < 4; ++i) {
      const int gm0 = m0 + wm + i * 16 + erow;
#pragma unroll
      for (int j = 0; j < 4; ++j) {
        const int gn = n0 + wn + j * 16 + ecol;
        const float bv = biasv[gn];
#pragma unroll
        for (int r = 0; r < 4; ++r)
          QKb[(size_t)(gm0 + r) * 2048 + gn] =
              __float2bfloat16((acc[i][j][r] + bv) * sc);
      }
    }
  } else {
#pragma unroll
    for (int i = 0; i < 4; ++i) {
      const int gm0 = m0 + wm + i * 16 + erow;
      const int bb = gm0 >> 11;
      const int t = gm0 & 2047;
#pragma unroll
      for (int j = 0; j < 4; ++j) {
        const int gn = n0 + wn + j * 16 + ecol;
        const float bv = biasv[gn];
        const int d = gn - 2048;
        __align__(8) bf16 tmp[4];
#pragma unroll
        for (int r = 0; r < 4; ++r)
          tmp[r] = __float2bfloat16(acc[i][j][r] + bv);
        *(ushort4*)(Vt + ((size_t)(bb * 1024 + d)) * 2048 + t) =
            *(const ushort4*)tmp;
      }
    }
  }
}

// ---------------------------------------------------------------------------
// Out projection: C(4096x1024) f32 = A(4096x1024)@(1024x1024)^T + bo.
// 128x64 tile, BK=64, dbuf, XCD-swizzled (2 n-blocks per XCD). 1D grid 512.
__global__ __launch_bounds__(256) void gemm_out(const bf16* __restrict__ A,
                                                const bf16* __restrict__ W,
                                                const float* __restrict__ biasv,
                                                float* __restrict__ C) {
  __shared__ __align__(16) bf16 As[2][128 * 64];  // 2 x 16 KB
  __shared__ __align__(16) bf16 Bs[2][64 * 64];   // 2 x 8 KB
  const int lin = blockIdx.x;
  const int xcd = lin & 7;
  const int kk = lin >> 3;  // 0..63
  const int m0 = (kk >> 1) * 128;
  const int n0 = (xcd * 2 + (kk & 1)) * 64;
  const int tid = threadIdx.x, lane = tid & 63, w = tid >> 6;
  const int wm = (w >> 1) * 64, wn = (w & 1) * 32;
  const int fr = lane & 15;
  const int ck = lane >> 4;

  f32x4 acc[4][2];
  const f32x4 fzero = {0.f, 0.f, 0.f, 0.f};
#pragma unroll
  for (int i = 0; i < 4; ++i)
#pragma unroll
    for (int j = 0; j < 2; ++j) acc[i][j] = fzero;

  auto stage = [&](int it, int buf) {
    const int k0 = it * 64;
#pragma unroll
    for (int is = 0; is < 4; ++is) {
      const int off = is * 4096 + w * 1024;
      const int row = (off >> 7) + (lane >> 3);
      const int sch = ((lane & 7) ^ (row & 7)) * 8;
      async_copy16(A + (size_t)(m0 + row) * 1024 + k0 + sch,
                   (char*)As[buf] + off);
      if (is < 2)
        async_copy16(W + (size_t)(n0 + row) * 1024 + k0 + sch,
                     (char*)Bs[buf] + off);
    }
  };

  stage(0, 0);
  __syncthreads();
  for (int it = 0; it < 16; ++it) {
    const int cur = it & 1;
    if (it + 1 < 16) stage(it + 1, cur ^ 1);
#pragma unroll
    for (int ks = 0; ks < 2; ++ks) {
      bf16x8 af[4], bfr[2];
      const int swk0 = (((ks * 4 + ck) ^ (fr & 7))) * 8;
#pragma unroll
      for (int i = 0; i < 4; ++i)
        af[i] = *(const bf16x8*)(As[cur] + (wm + i * 16 + fr) * 64 + swk0);
#pragma unroll
      for (int j = 0; j < 2; ++j)
        bfr[j] = *(const bf16x8*)(Bs[cur] + (wn + j * 16 + fr) * 64 + swk0);
#pragma unroll
      for (int i = 0; i < 4; ++i)
#pragma unroll
        for (int j = 0; j < 2; ++j)
          acc[i][j] = mfma16x16x32(af[i], bfr[j], acc[i][j]);
    }
    __syncthreads();
  }
  const int erow = (lane >> 4) * 4;
  const int ecol = lane & 15;
#pragma unroll
  for (int i = 0; i < 4; ++i) {
    const int gm0 = m0 + wm + i * 16 + erow;
#pragma unroll
    for (int j = 0; j < 2; ++j) {
      const int gn = n0 + wn + j * 16 + ecol;
      const float bv = biasv[gn];
#pragma unroll
      for (int r = 0; r < 4; ++r)
        C[(size_t)(gm0 + r) * 1024 + gn] = acc[i][j][r] + bv;
    }
  }
}

// ---------------------------------------------------------------------------
// Flash attention, S^T formulation, no-max softmax, key-split, TWO HEADS per
// block: one bias fetch serves both heads' S C-init (bias has no head index)
// -> bias traffic and bias load latency halve. LDS-P (proven R7 path).
// Per key-iter: stage K/V for both heads (single-buffer, 2-barrier), then
// per head: S = K.Q^T + bias, exp -> Ps (stride 72, conflict-free), PV.
// Ps reused serially across heads within the wave (no barrier needed).
// 1D grid 512 = 16 qblk x 2 half x 8 head-pairs x 2 b. LDS 50.7 KB.
__global__ __launch_bounds__(256) void flash_attn(
    const bf16* __restrict__ Qm, const bf16* __restrict__ Km,
    const bf16* __restrict__ Vtm, const bf16* __restrict__ biasS,
    float* __restrict__ Op0, float* __restrict__ Op1,
    float* __restrict__ lpart) {
  __shared__ __align__(16) bf16 Ks[2][64 * 64];   // per head, 16 KB
  __shared__ __align__(16) bf16 Vs[2][64 * 64];   // per head, 16 KB
  __shared__ __align__(16) bf16 Ps[4 * 32 * 72];  // per-wave P^T, 18 KB
  const int lin = blockIdx.x;
  const int xcd = lin & 7;
  const int kk = lin >> 3;        // 0..63
  const int cl = kk & 1;
  const int r2 = kk >> 1;         // 0..31
  const int half = r2 & 1;
  const int q0 = (r2 >> 1) * 128;
  const int combo = xcd * 2 + cl; // 0..15
  const int hp = combo & 7;       // head pair
  const int b = combo >> 3;
  const int tid = threadIdx.x, lane = tid & 63, w = tid >> 6;
  const int ql = lane & 15, qk = lane >> 4;
  const int T = 2048, D = 1024;
  const int sw0 = (qk ^ (ql & 7)) * 8;
  const int sw1 = ((qk + 4) ^ (ql & 7)) * 8;

  // Q B-frags for both heads: B[n=q][k=d], 2 q-subtiles x 2 k-steps
  bf16x8 qf[2][2][2];  // [head][qt][ks]
#pragma unroll
  for (int hh = 0; hh < 2; ++hh)
#pragma unroll
    for (int qt = 0; qt < 2; ++qt)
#pragma unroll
      for (int ks = 0; ks < 2; ++ks)
        qf[hh][qt][ks] = *(const bf16x8*)(
            Qm + (size_t)(b * T + q0 + w * 32 + qt * 16 + ql) * 2048 +
            (hp * 2 + hh) * 64 + ks * 32 + qk * 8);

  f32x4 acc[2][4][2];  // [head][dt][qt]
  const f32x4 fzero = {0.f, 0.f, 0.f, 0.f};
#pragma unroll
  for (int hh = 0; hh < 2; ++hh)
#pragma unroll
    for (int dt = 0; dt < 4; ++dt)
#pragma unroll
      for (int qt = 0; qt < 2; ++qt) acc[hh][dt][qt] = fzero;
  float lp[2][2] = {{0.f, 0.f}, {0.f, 0.f}};

  const bf16* kbase0 = Km + (size_t)(b * T) * 2048 + (hp * 2) * 64;
  const bf16* vbase0 = Vtm + (size_t)(b * D + hp * 2 * 64) * 2048;
  const bf16* bb0 = biasS + (size_t)(b * T + q0 + w * 32 + ql) * 2048 + qk * 4;
  bf16* pb = Ps + w * 2304;

  for (int j = 0; j < 16; ++j) {
    const int jj = half * 16 + j;  // global key-block
    __syncthreads();
#pragma unroll
    for (int hh = 0; hh < 2; ++hh)
#pragma unroll
      for (int is = 0; is < 2; ++is) {
        const int off = is * 4096 + w * 1024;
        const int row = (off >> 7) + (lane >> 3);
        const int sch = ((lane & 7) ^ (row & 7)) * 8;
        async_copy16(kbase0 + (size_t)(jj * 64 + row) * 2048 + hh * 64 + sch,
                     (char*)Ks[hh] + off);
        async_copy16(vbase0 + (size_t)(hh * 64 + row) * 2048 + jj * 64 + sch,
                     (char*)Vs[hh] + off);
      }
    // bias prefetch: ONE fetch for BOTH heads (overlaps staging drain)
    ushort4 bq[2][4];
#pragma unroll
    for (int qt = 0; qt < 2; ++qt)
#pragma unroll
      for (int jt = 0; jt < 4; ++jt)
        bq[qt][jt] = *(const ushort4*)(bb0 + (size_t)qt * 16 * 2048 + jj * 64 +
                                       jt * 16);
    __syncthreads();
#pragma unroll
    for (int hh = 0; hh < 2; ++hh) {
      const bf16* ksp = Ks[hh];
      const bf16* vsp = Vs[hh];
      // S^T tiles: rows=key, cols=q; bias as MFMA C-init (shared)
#pragma unroll
      for (int jt = 0; jt < 4; ++jt) {
        const bf16x8 kf0 = *(const bf16x8*)(ksp + (jt * 16 + ql) * 64 + sw0);
        const bf16x8 kf1 = *(const bf16x8*)(ksp + (jt * 16 + ql) * 64 + sw1);
#pragma unroll
        for (int qt = 0; qt < 2; ++qt) {
          f32x4 c;
          c[0] = bfu2f(bq[qt][jt].x); c[1] = bfu2f(bq[qt][jt].y);
          c[2] = bfu2f(bq[qt][jt].z); c[3] = bfu2f(bq[qt][jt].w);
          c = mfma16x16x32(kf0, qf[hh][qt][0], c);
          c = mfma16x16x32(kf1, qf[hh][qt][1], c);
          __align__(8) bf16 t4[4];
#pragma unroll
          for (int r = 0; r < 4; ++r) {
            const float pv = __builtin_amdgcn_exp2f(c[r]);
            lp[hh][qt] += pv;
            t4[r] = __float2bfloat16(pv);
          }
          *(ushort4*)(pb + (qt * 16 + ql) * 72 + jt * 16 + qk * 4) =
              *(const ushort4*)t4;
        }
      }
      // O[q][d] += P.V^T ; V-frags shared across q-subtiles
#pragma unroll
      for (int ks = 0; ks < 2; ++ks) {
        const bf16x8 pf0 = *(const bf16x8*)(pb + ql * 72 + ks * 32 + qk * 8);
        const bf16x8 pf1 =
            *(const bf16x8*)(pb + (16 + ql) * 72 + ks * 32 + qk * 8);
        const int sw = ks ? sw1 : sw0;
#pragma unroll
        for (int dt = 0; dt < 4; ++dt) {
          const bf16x8 vf = *(const bf16x8*)(vsp + (dt * 16 + ql) * 64 + sw);
          acc[hh][dt][0] = mfma16x16x32(pf0, vf, acc[hh][dt][0]);
          acc[hh][dt][1] = mfma16x16x32(pf1, vf, acc[hh][dt][1]);
        }
      }
    }
  }
  // l partials: reduce across quads (lane's p-values all share q = ...+ql)
#pragma unroll
  for (int hh = 0; hh < 2; ++hh)
#pragma unroll
    for (int qt = 0; qt < 2; ++qt) {
      lp[hh][qt] += __shfl_xor(lp[hh][qt], 16);
      lp[hh][qt] += __shfl_xor(lp[hh][qt], 32);
    }
  if (qk == 0) {
#pragma unroll
    for (int hh = 0; hh < 2; ++hh)
#pragma unroll
      for (int qt = 0; qt < 2; ++qt)
        lpart[half * 65536 + (b * 16 + hp * 2 + hh) * 2048 + q0 + w * 32 +
              qt * 16 + ql] = lp[hh][qt];
  }
  float* Op = half ? Op1 : Op0;
#pragma unroll
  for (int hh = 0; hh < 2; ++hh)
#pragma unroll
    for (int qt = 0; qt < 2; ++qt)
#pragma unroll
      for (int r = 0; r < 4; ++r) {
        const size_t orow =
            (size_t)(b * T + q0 + w * 32 + qt * 16 + qk * 4 + r);
#pragma unroll
        for (int dt = 0; dt < 4; ++dt)
          Op[orow * 1024 + (hp * 2 + hh) * 64 + dt * 16 + ql] =
              acc[hh][dt][qt][r];
      }
}

// ---------------------------------------------------------------------------
// Combine key-half partials: AOut = bf16((O0+O1) / (l0+l1)). grid 4096 x 256.
__global__ __launch_bounds__(256) void combine(const float* __restrict__ O0,
                                               const float* __restrict__ O1,
                                               const float* __restrict__ lpart,
                                               bf16* __restrict__ AOut) {
  const int idx = blockIdx.x * 256 + threadIdx.x;  // 0..1048575
  const int row = idx >> 8;
  const int col = (idx & 255) * 4;
  const int b = row >> 11, q = row & 2047, h = col >> 6;
  const int li = (b * 16 + h) * 2048 + q;
  const float inv = __builtin_amdgcn_rcpf(lpart[li] + lpart[65536 + li]);
  const float4 a = *(const float4*)(O0 + (size_t)row * 1024 + col);
  const float4 c = *(const float4*)(O1 + (size_t)row * 1024 + col);
  __align__(8) bf16 t[4] = {
      __float2bfloat16((a.x + c.x) * inv), __float2bfloat16((a.y + c.y) * inv),
      __float2bfloat16((a.z + c.z) * inv), __float2bfloat16((a.w + c.w) * inv)};
  *(ushort4*)(AOut + (size_t)row * 1024 + col) = *(const ushort4*)t;
}

// ---------------------------------------------------------------------------
extern "C" void kernel_launch(void* const* d_in, const int* in_sizes, int n_in,
                              void* d_out, int out_size, void* d_ws,
                              size_t ws_size, hipStream_t stream) {
  (void)in_sizes; (void)n_in; (void)out_size; (void)ws_size;
  const float* Hx = (const float*)d_in[0];
  const float* Hf = (const float*)d_in[1];
  const float* Gm = (const float*)d_in[2];
  const float* Wg = (const float*)d_in[3];
  const float* bg = (const float*)d_in[4];
  const float* Wq = (const float*)d_in[5];
  const float* bq = (const float*)d_in[6];
  const float* Wk = (const float*)d_in[7];
  const float* bk = (const float*)d_in[8];
  const float* Wv = (const float*)d_in[9];
  const float* bv = (const float*)d_in[10];
  const float* Wo = (const float*)d_in[11];
  const float* bo = (const float*)d_in[12];
  float* out = (float*)d_out;

  char* p = (char*)d_ws;
  bf16* hcat = (bf16*)p;   p += (size_t)4096 * 2048 * 2;  // (B*T, 2D)
  bf16* QKb = (bf16*)p;    p += (size_t)4096 * 2048 * 2;  // (B*T, Q|K)
  bf16* Vtb = (bf16*)p;    p += (size_t)4096 * 1024 * 2;  // (B, D, T)
  bf16* biasS = (bf16*)p;  p += (size_t)4096 * 2048 * 2;  // (B*T, T) * log2e
  bf16* AOut = (bf16*)p;   p += (size_t)4096 * 1024 * 2;
  bf16* Wqkvb = (bf16*)p;  p += (size_t)3072 * 2048 * 2;  // (3N, K) packed
  bf16* Wob = (bf16*)p;    p += (size_t)1024 * 1024 * 2;
  bf16* Wgb = (bf16*)p;    p += (size_t)2048 * 256 * 2;
  bf16* Gmb = (bf16*)p;    p += (size_t)4096 * 256 * 2;
  float* qkvbias = (float*)p; p += (size_t)3072 * 4;
  float* Op1 = (float*)p;  p += (size_t)4096 * 1024 * 4;  // key-half-1 partial
  float* lpart = (float*)p; p += (size_t)2 * 65536 * 4;   // l partials
  float* Op0 = (float*)hcat;  // hcat is dead after gemm_qkv_bias; 16.8 MB fits

  pack_hx<<<dim3(32, 16, 2), 256, 0, stream>>>(Hx, hcat);
  pack_all<<<dim3(12803), 256, 0, stream>>>(Hf, Wq, Wk, Wv, Wo, Wg, Gm, bq, bk,
                                            bv, hcat, Wqkvb, Wob, Wgb, Gmb,
                                            qkvbias);
  // QKV projection + attention-bias GEMM, one dispatch, XCD-swizzled
  gemm_qkv_bias<<<dim3(1280), 256, 0, stream>>>(hcat, Wqkvb, qkvbias, Gmb,
                                                Wgb, bg, QKb, Vtb, biasS);
  // fused attention, key-split halves, 2 heads/block (bias shared)
  flash_attn<<<dim3(512), 256, 0, stream>>>(QKb, QKb + 1024, Vtb, biasS,
                                            Op0, Op1, lpart);
  // combine partials -> AOut bf16
  combine<<<dim3(4096), 256, 0, stream>>>(Op0, Op1, lpart, AOut);
  // output projection (fp32 out), XCD-swizzled
  gemm_out<<<dim3(512), 256, 0, stream>>>(AOut, Wob, bo, out);
}